// Round 9
// baseline (600.444 us; speedup 1.0000x reference)
//
#include <hip/hip_runtime.h>

#define NB  64
#define IC  2048
#define ID  16
#define DD  256
#define DDSQ 65536
#define PB  (DDSQ * NB)       // 4,194,304 floats = one full-batch fp32-sized buffer
#define NSQ 11                // matrix squarings
#define NPI 7                 // finish matvecs: exponent 2^11 * 8 = 16384

typedef __attribute__((ext_vector_type(8))) short          s16x8;  // 8 bf16 (4 VGPRs) MFMA frag
typedef __attribute__((ext_vector_type(4))) float          f32x4;  // MFMA acc
typedef __attribute__((ext_vector_type(4))) unsigned short us4;
typedef __attribute__((ext_vector_type(8))) unsigned short us8;

// fp32 -> bf16 (RNE) and back, via raw bits
__device__ __forceinline__ unsigned short f2b(float f) {
    union { float f; unsigned u; } c; c.f = f;
    const unsigned u = c.u + 0x7FFFu + ((c.u >> 16) & 1u);
    return (unsigned short)(u >> 16);
}
__device__ __forceinline__ float b2f(unsigned short h) {
    union { unsigned u; float f; } c; c.u = ((unsigned)h) << 16;
    return c.f;
}
// fp32 -> packed (hi bf16 << 16) | (lo bf16): 2-term split in one u32
__device__ __forceinline__ unsigned f2pk(float f) {
    const unsigned short h = f2b(f);
    const unsigned short l = f2b(f - b2f(h));
    return ((unsigned)h << 16) | (unsigned)l;
}

// ---------------- stage 1: u[b,c,:] = x[b,c,:] @ W_c (ALL 64 batches/block) -
// One block per capsule c (2048 blocks): W row read ONCE (HBM 288 -> 168 MB).
// Same i-ascending fmaf chain per output element => bit-identical U.
__global__ __launch_bounds__(256, 4) void u_kernel(const float* __restrict__ caps,
                                                   const float* __restrict__ W,
                                                   unsigned* __restrict__ U) {
    const int c = blockIdx.x;
    const int t = threadIdx.x;
    __shared__ float xsT[ID][64];        // [dim][batch] (4 KB)
    {
        const int b = t >> 2, q = (t & 3) * 4;
        const float4 x4 = *(const float4*)&caps[((size_t)b * IC + c) * ID + q];
        xsT[q + 0][b] = x4.x; xsT[q + 1][b] = x4.y;
        xsT[q + 2][b] = x4.z; xsT[q + 3][b] = x4.w;
    }
    __syncthreads();
    float a[64];
#pragma unroll
    for (int b = 0; b < 64; ++b) a[b] = 0.f;
#pragma unroll
    for (int i = 0; i < ID; ++i) {
        const float wi = W[((size_t)c * ID + i) * DD + t];    // coalesced over t
#pragma unroll
        for (int g = 0; g < 16; ++g) {
            const float4 x = *(const float4*)&xsT[i][g * 4];
            a[g * 4 + 0] = fmaf(x.x, wi, a[g * 4 + 0]);
            a[g * 4 + 1] = fmaf(x.y, wi, a[g * 4 + 1]);
            a[g * 4 + 2] = fmaf(x.z, wi, a[g * 4 + 2]);
            a[g * 4 + 3] = fmaf(x.w, wi, a[g * 4 + 3]);
        }
    }
#pragma unroll
    for (int b = 0; b < 64; ++b)
        U[((size_t)b * IC + c) * DD + t] = f2pk(a[b]);
}

// ---- stage 2: C = U^T U (full K), bf16 hi/lo out + trace, 512 blocks -------
// Register-transpose staging + T14 prefetch (proven clean rounds 4/6/7/8).
__global__ __launch_bounds__(256, 2)
void cmb_kernel(const unsigned* __restrict__ Up,
                unsigned short* __restrict__ Ch, unsigned short* __restrict__ Cl,
                float* __restrict__ Sc) {
    const int id   = blockIdx.x;
    const int bb   = id & 63;
    const int tile = id >> 6;            // 0..7 (2x4 of 128x64)
    const int tr = tile >> 2, tc = tile & 3;
    const int d0 = tr * 128, e0 = tc * 64;
    const int t    = threadIdx.x;
    const int lane = t & 63, wid = t >> 6;
    const int wm = wid >> 1, wn = wid & 1;            // 2x2 wave grid
    const int fr = lane & 15, kg = lane >> 4;         // frag row, k-group
    const int sl8 = lane & 7, qg = lane >> 3;         // staging: row-in-octet, k-quad
    const size_t mb = (size_t)bb * DDSQ;

    __shared__ unsigned short Ah[128][40];   // [d][k], pitch 40 shorts (80 B)
    __shared__ unsigned short Al[128][40];
    __shared__ unsigned short Bh[64][40];    // [e][k]
    __shared__ unsigned short Bl[64][40];
    __shared__ float red[256];

    const f32x4 z4 = {0.f, 0.f, 0.f, 0.f};
    f32x4 acc[4][2];
#pragma unroll
    for (int m = 0; m < 4; ++m)
#pragma unroll
        for (int n = 0; n < 2; ++n) acc[m][n] = z4;

    const unsigned* Ub = Up + (size_t)bb * IC * DD;
    unsigned va[4][4], vb[2][4];
    auto loadU = [&](int kb) {
#pragma unroll
        for (int s = 0; s < 4; ++s) {
            const int row = wid * 8 + sl8 + 32 * s;       // d-local 0..127
#pragma unroll
            for (int j = 0; j < 4; ++j)
                va[s][j] = Ub[(size_t)(kb + 4 * qg + j) * DD + d0 + row];
        }
#pragma unroll
        for (int s = 0; s < 2; ++s) {
            const int row = wid * 8 + sl8 + 32 * s;       // e-local 0..63
#pragma unroll
            for (int j = 0; j < 4; ++j)
                vb[s][j] = Ub[(size_t)(kb + 4 * qg + j) * DD + e0 + row];
        }
    };

    loadU(0);
    for (int kb = 0; kb < IC; kb += 32) {
        __syncthreads();
#pragma unroll
        for (int s = 0; s < 4; ++s) {
            const int row = wid * 8 + sl8 + 32 * s;
            us4 h, l;
#pragma unroll
            for (int j = 0; j < 4; ++j) {
                h[j] = (unsigned short)(va[s][j] >> 16);
                l[j] = (unsigned short)(va[s][j] & 0xFFFFu);
            }
            *(us4*)&Ah[row][4 * qg] = h;
            *(us4*)&Al[row][4 * qg] = l;
        }
#pragma unroll
        for (int s = 0; s < 2; ++s) {
            const int row = wid * 8 + sl8 + 32 * s;
            us4 h, l;
#pragma unroll
            for (int j = 0; j < 4; ++j) {
                h[j] = (unsigned short)(vb[s][j] >> 16);
                l[j] = (unsigned short)(vb[s][j] & 0xFFFFu);
            }
            *(us4*)&Bh[row][4 * qg] = h;
            *(us4*)&Bl[row][4 * qg] = l;
        }
        __syncthreads();
        if (kb + 32 < IC) loadU(kb + 32);     // T14: next loads fly under MFMA
        s16x8 ah[4], al[4], bh[2], bl[2];
#pragma unroll
        for (int m = 0; m < 4; ++m) {
            const int r = wm * 64 + m * 16 + fr;
            ah[m] = *(const s16x8*)&Ah[r][kg * 8];
            al[m] = *(const s16x8*)&Al[r][kg * 8];
        }
#pragma unroll
        for (int n = 0; n < 2; ++n) {
            const int r = wn * 32 + n * 16 + fr;
            bh[n] = *(const s16x8*)&Bh[r][kg * 8];
            bl[n] = *(const s16x8*)&Bl[r][kg * 8];
        }
#pragma unroll
        for (int m = 0; m < 4; ++m)
#pragma unroll
            for (int n = 0; n < 2; ++n) {
                acc[m][n] = __builtin_amdgcn_mfma_f32_16x16x32_bf16(ah[m], bh[n], acc[m][n], 0, 0, 0);
                acc[m][n] = __builtin_amdgcn_mfma_f32_16x16x32_bf16(ah[m], bl[n], acc[m][n], 0, 0, 0);
                acc[m][n] = __builtin_amdgcn_mfma_f32_16x16x32_bf16(al[m], bh[n], acc[m][n], 0, 0, 0);
            }
    }

    // epilogue: bf16 hi/lo store (UNSCALED C) + fp32 trace
    float ts = 0.f;
    const int row_l = wm * 64 + (lane >> 4) * 4;
    const int col_l = wn * 32 + fr;
#pragma unroll
    for (int m = 0; m < 4; ++m)
#pragma unroll
        for (int n = 0; n < 2; ++n)
#pragma unroll
            for (int r = 0; r < 4; ++r) {
                const int gr = d0 + row_l + m * 16 + r;
                const int gc = e0 + col_l + n * 16;
                const float e = acc[m][n][r];
                const unsigned short h = f2b(e);
                const unsigned short l = f2b(e - b2f(h));
                const size_t o = mb + (size_t)gr * DD + gc;
                Ch[o] = h; Cl[o] = l;
                if (gr == gc) ts += e;
            }
    if ((tc >> 1) == tr) {
        red[t] = ts;
        __syncthreads();
        for (int s2 = 128; s2 > 0; s2 >>= 1) {
            if (t < s2) red[t] += red[t + s2];
            __syncthreads();
        }
        if (t == 0) atomicAdd(&Sc[bb], red[0]);
    }
}

// ---- E = (D/s)^2, 64x64 tile, LDS-FREE direct fragment loads ---------------
// A and B frags are both row-slices of symmetric row-major D: lane (fr,kg)
// loads D[row][kb+kg*8..+7] as one aligned b128 straight from global — the
// LDS staging bought zero reuse (each element consumed once per wave) and
// cost 2 barriers x 8 k-steps. No __syncthreads in the k-loop; identical
// values, identical MFMA order => bit-identical output.
__global__ __launch_bounds__(256, 4)
void sqm_kernel(const unsigned short* __restrict__ Dh, const unsigned short* __restrict__ Dl,
                unsigned short* __restrict__ Eh, unsigned short* __restrict__ El,
                const float* __restrict__ s_in, float* __restrict__ s_out) {
    const int id   = blockIdx.x;          // 1024 = 64 batches x 16 tiles
    const int bb   = id & 63;             // id%8 == bb%8 -> batch XCD-local
    const int tile = id >> 6;             // 0..15 (4x4 of 64x64)
    const int tr = tile >> 2, tc = tile & 3;
    const int d0 = tr * 64, e0 = tc * 64;
    const int t    = threadIdx.x;
    const int lane = t & 63, wid = t >> 6;
    const int wm = wid >> 1, wn = wid & 1;            // 2x2 wave grid, 32x32/wave
    const int fr = lane & 15, kg = lane >> 4;
    const size_t mb = (size_t)bb * DDSQ;

    __shared__ float red[256];            // trace reduction only

    const f32x4 z4 = {0.f, 0.f, 0.f, 0.f};
    f32x4 acc[2][2];
#pragma unroll
    for (int m = 0; m < 2; ++m)
#pragma unroll
        for (int n = 0; n < 2; ++n) acc[m][n] = z4;

    const float s   = s_in[bb];
    const float inv = 1.f / (s * s);

    // per-lane fragment row bases (elements)
    const size_t baseA0 = mb + (size_t)(d0 + wm * 32 +  0 + fr) * DD;
    const size_t baseA1 = mb + (size_t)(d0 + wm * 32 + 16 + fr) * DD;
    const size_t baseB0 = mb + (size_t)(e0 + wn * 32 +  0 + fr) * DD;
    const size_t baseB1 = mb + (size_t)(e0 + wn * 32 + 16 + fr) * DD;

#pragma unroll
    for (int kb = 0; kb < DD; kb += 32) {
        const int ko = kb + kg * 8;
        s16x8 ah[2], al[2], bh[2], bl[2];
        ah[0] = *(const s16x8*)&Dh[baseA0 + ko];
        al[0] = *(const s16x8*)&Dl[baseA0 + ko];
        ah[1] = *(const s16x8*)&Dh[baseA1 + ko];
        al[1] = *(const s16x8*)&Dl[baseA1 + ko];
        bh[0] = *(const s16x8*)&Dh[baseB0 + ko];
        bl[0] = *(const s16x8*)&Dl[baseB0 + ko];
        bh[1] = *(const s16x8*)&Dh[baseB1 + ko];
        bl[1] = *(const s16x8*)&Dl[baseB1 + ko];
#pragma unroll
        for (int m = 0; m < 2; ++m)
#pragma unroll
            for (int n = 0; n < 2; ++n) {
                acc[m][n] = __builtin_amdgcn_mfma_f32_16x16x32_bf16(ah[m], bh[n], acc[m][n], 0, 0, 0);
                acc[m][n] = __builtin_amdgcn_mfma_f32_16x16x32_bf16(ah[m], bl[n], acc[m][n], 0, 0, 0);
                acc[m][n] = __builtin_amdgcn_mfma_f32_16x16x32_bf16(al[m], bh[n], acc[m][n], 0, 0, 0);
            }
    }

    // epilogue: scale, trace, split to hi/lo bf16
    float ts = 0.f;
    const int row_l = wm * 32 + (lane >> 4) * 4;
    const int col_l = wn * 32 + fr;
#pragma unroll
    for (int m = 0; m < 2; ++m)
#pragma unroll
        for (int n = 0; n < 2; ++n)
#pragma unroll
            for (int r = 0; r < 4; ++r) {
                const int gr = d0 + row_l + m * 16 + r;
                const int gc = e0 + col_l + n * 16;
                const float e = acc[m][n][r] * inv;
                const unsigned short h = f2b(e);
                const unsigned short l = f2b(e - b2f(h));
                const size_t o = mb + (size_t)gr * DD + gc;
                Eh[o] = h; El[o] = l;
                if (gr == gc) ts += e;
            }
    if (tr == tc) {                       // 64x64 diag tiles partition diagonal
        red[t] = ts;
        __syncthreads();
        for (int s2 = 128; s2 > 0; s2 >>= 1) {
            if (t < s2) red[t] += red[t + s2];
            __syncthreads();
        }
        if (t == 0) atomicAdd(&s_out[bb], red[0]);
    }
}

// ------- finish: column start + NPI matvecs (no renorm; lambda1 ~ 1) --------
__global__ __launch_bounds__(256, 2) void finish_kernel(const unsigned short* __restrict__ Dh,
                                                        const unsigned short* __restrict__ Dl,
                                                        float* __restrict__ out) {
    const int b = blockIdx.x, t = threadIdx.x;
    const size_t mb = (size_t)b * DDSQ;
    __shared__ float vs[DD];
    __shared__ float red[DD];
    __shared__ int   ridx[DD];
    red[t] = b2f(Dh[mb + (size_t)t * DD + t]) + b2f(Dl[mb + (size_t)t * DD + t]);
    ridx[t] = t;
    __syncthreads();
    for (int s = 128; s > 0; s >>= 1) {
        if (t < s && red[t + s] > red[t]) { red[t] = red[t + s]; ridx[t] = ridx[t + s]; }
        __syncthreads();
    }
    const int jmax0 = ridx[0];
    __syncthreads();
    float v = b2f(Dh[mb + (size_t)jmax0 * DD + t]) + b2f(Dl[mb + (size_t)jmax0 * DD + t]);
    for (int it = 0; it < NPI; ++it) {
        vs[t] = v;
        __syncthreads();
        float a = 0.f;
        const unsigned short* rh = Dh + mb + (size_t)t * DD;
        const unsigned short* rl = Dl + mb + (size_t)t * DD;
#pragma unroll 4
        for (int j = 0; j < DD; j += 8) {
            const us8 h8 = *(const us8*)&rh[j];
            const us8 l8 = *(const us8*)&rl[j];
            a = fmaf(b2f(h8[0]) + b2f(l8[0]), vs[j + 0], a);
            a = fmaf(b2f(h8[1]) + b2f(l8[1]), vs[j + 1], a);
            a = fmaf(b2f(h8[2]) + b2f(l8[2]), vs[j + 2], a);
            a = fmaf(b2f(h8[3]) + b2f(l8[3]), vs[j + 3], a);
            a = fmaf(b2f(h8[4]) + b2f(l8[4]), vs[j + 4], a);
            a = fmaf(b2f(h8[5]) + b2f(l8[5]), vs[j + 5], a);
            a = fmaf(b2f(h8[6]) + b2f(l8[6]), vs[j + 6], a);
            a = fmaf(b2f(h8[7]) + b2f(l8[7]), vs[j + 7], a);
        }
        __syncthreads();
        v = a;
    }
    vs[t] = v;
    red[t] = v * v;
    __syncthreads();
    for (int s = 128; s > 0; s >>= 1) {
        if (t < s) red[t] += red[t + s];
        __syncthreads();
    }
    const float nrm = sqrtf(red[0]);
    __syncthreads();
    red[t] = fabsf(v);
    ridx[t] = t;
    __syncthreads();
    for (int s = 128; s > 0; s >>= 1) {
        if (t < s && red[t + s] > red[t]) { red[t] = red[t + s]; ridx[t] = ridx[t + s]; }
        __syncthreads();
    }
    const float sgn = (vs[ridx[0]] < 0.f) ? -1.f : 1.f;
    out[(size_t)b * DD + t] = sgn * v / nrm;
}

extern "C" void kernel_launch(void* const* d_in, const int* in_sizes, int n_in,
                              void* d_out, int out_size, void* d_ws, size_t ws_size,
                              hipStream_t stream) {
    const float* caps = (const float*)d_in[0];   // (64, 2048, 16)
    const float* W    = (const float*)d_in[1];   // (2048, 16, 256)
    float* out = (float*)d_out;                  // (64, 256)
    float* ws  = (float*)d_ws;

    // layout: Up packed = 8*PB @0 | X @8PB | Y @9PB | Sc @10PB  (~168 MB)
    unsigned* Up = (unsigned*)ws;
    unsigned short* Xh = (unsigned short*)(ws + (size_t)8 * PB);
    unsigned short* Xl = Xh + (size_t)NB * DDSQ;
    unsigned short* Yh = (unsigned short*)(ws + (size_t)9 * PB);
    unsigned short* Yl = Yh + (size_t)NB * DDSQ;
    float* Sc = ws + (size_t)10 * PB;

    hipMemsetAsync(Sc, 0, 2048 * sizeof(float), stream);

    u_kernel<<<IC, 256, 0, stream>>>(caps, W, Up);
    cmb_kernel<<<512, 256, 0, stream>>>(Up, Xh, Xl, Sc);   // C (unscaled) -> X

    unsigned short* ph = Xh; unsigned short* pl = Xl;
    unsigned short* qh = Yh; unsigned short* ql = Yl;
    for (int it = 0; it < NSQ; ++it) {
        sqm_kernel<<<1024, 256, 0, stream>>>(ph, pl, qh, ql,
                                             Sc + it * 64, Sc + (it + 1) * 64);
        unsigned short* t1 = ph; ph = qh; qh = t1;
        unsigned short* t2 = pl; pl = ql; ql = t2;
    }

    finish_kernel<<<NB, 256, 0, stream>>>(ph, pl, out);
}

// Round 10
// 382.221 us; speedup vs baseline: 1.5709x; 1.5709x over previous
//
#include <hip/hip_runtime.h>

#define NB  64
#define IC  2048
#define ID  16
#define DD  256
#define DDSQ 65536
#define PB  (DDSQ * NB)       // 4,194,304 floats = one full-batch fp32-sized buffer
#define NSQ 11                // matrix squarings
#define NPI 7                 // finish matvecs: exponent 2^11 * 8 = 16384

typedef __attribute__((ext_vector_type(8))) short          s16x8;  // 8 bf16 (4 VGPRs) MFMA frag
typedef __attribute__((ext_vector_type(4))) float          f32x4;  // MFMA acc
typedef __attribute__((ext_vector_type(4))) unsigned short us4;
typedef __attribute__((ext_vector_type(8))) unsigned short us8;

// fp32 -> bf16 (RNE) and back, via raw bits
__device__ __forceinline__ unsigned short f2b(float f) {
    union { float f; unsigned u; } c; c.f = f;
    const unsigned u = c.u + 0x7FFFu + ((c.u >> 16) & 1u);
    return (unsigned short)(u >> 16);
}
__device__ __forceinline__ float b2f(unsigned short h) {
    union { unsigned u; float f; } c; c.u = ((unsigned)h) << 16;
    return c.f;
}
// fp32 -> packed (hi bf16 << 16) | (lo bf16): 2-term split in one u32
__device__ __forceinline__ unsigned f2pk(float f) {
    const unsigned short h = f2b(f);
    const unsigned short l = f2b(f - b2f(h));
    return ((unsigned)h << 16) | (unsigned)l;
}

// ---------------- stage 1: u[b,c,:] = x[b,c,:] @ W_c (ALL 64 batches/block) -
// One block per capsule c (2048 blocks): W row read ONCE (HBM 288 -> 168 MB).
// Same i-ascending fmaf chain per output element => bit-identical U.
__global__ __launch_bounds__(256, 4) void u_kernel(const float* __restrict__ caps,
                                                   const float* __restrict__ W,
                                                   unsigned* __restrict__ U) {
    const int c = blockIdx.x;
    const int t = threadIdx.x;
    __shared__ float xsT[ID][64];        // [dim][batch] (4 KB)
    {
        const int b = t >> 2, q = (t & 3) * 4;
        const float4 x4 = *(const float4*)&caps[((size_t)b * IC + c) * ID + q];
        xsT[q + 0][b] = x4.x; xsT[q + 1][b] = x4.y;
        xsT[q + 2][b] = x4.z; xsT[q + 3][b] = x4.w;
    }
    __syncthreads();
    float a[64];
#pragma unroll
    for (int b = 0; b < 64; ++b) a[b] = 0.f;
#pragma unroll
    for (int i = 0; i < ID; ++i) {
        const float wi = W[((size_t)c * ID + i) * DD + t];    // coalesced over t
#pragma unroll
        for (int g = 0; g < 16; ++g) {
            const float4 x = *(const float4*)&xsT[i][g * 4];
            a[g * 4 + 0] = fmaf(x.x, wi, a[g * 4 + 0]);
            a[g * 4 + 1] = fmaf(x.y, wi, a[g * 4 + 1]);
            a[g * 4 + 2] = fmaf(x.z, wi, a[g * 4 + 2]);
            a[g * 4 + 3] = fmaf(x.w, wi, a[g * 4 + 3]);
        }
    }
#pragma unroll
    for (int b = 0; b < 64; ++b)
        U[((size_t)b * IC + c) * DD + t] = f2pk(a[b]);
}

// ---- stage 2: C = U^T U (full K), bf16 hi/lo out + trace, 512 blocks -------
// Register-transpose staging + T14 prefetch (proven clean rounds 4/6/7/8/9).
__global__ __launch_bounds__(256, 2)
void cmb_kernel(const unsigned* __restrict__ Up,
                unsigned short* __restrict__ Ch, unsigned short* __restrict__ Cl,
                float* __restrict__ Sc) {
    const int id   = blockIdx.x;
    const int bb   = id & 63;
    const int tile = id >> 6;            // 0..7 (2x4 of 128x64)
    const int tr = tile >> 2, tc = tile & 3;
    const int d0 = tr * 128, e0 = tc * 64;
    const int t    = threadIdx.x;
    const int lane = t & 63, wid = t >> 6;
    const int wm = wid >> 1, wn = wid & 1;            // 2x2 wave grid
    const int fr = lane & 15, kg = lane >> 4;         // frag row, k-group
    const int sl8 = lane & 7, qg = lane >> 3;         // staging: row-in-octet, k-quad
    const size_t mb = (size_t)bb * DDSQ;

    __shared__ unsigned short Ah[128][40];   // [d][k], pitch 40 shorts (80 B)
    __shared__ unsigned short Al[128][40];
    __shared__ unsigned short Bh[64][40];    // [e][k]
    __shared__ unsigned short Bl[64][40];
    __shared__ float red[256];

    const f32x4 z4 = {0.f, 0.f, 0.f, 0.f};
    f32x4 acc[4][2];
#pragma unroll
    for (int m = 0; m < 4; ++m)
#pragma unroll
        for (int n = 0; n < 2; ++n) acc[m][n] = z4;

    const unsigned* Ub = Up + (size_t)bb * IC * DD;
    unsigned va[4][4], vb[2][4];
    auto loadU = [&](int kb) {
#pragma unroll
        for (int s = 0; s < 4; ++s) {
            const int row = wid * 8 + sl8 + 32 * s;       // d-local 0..127
#pragma unroll
            for (int j = 0; j < 4; ++j)
                va[s][j] = Ub[(size_t)(kb + 4 * qg + j) * DD + d0 + row];
        }
#pragma unroll
        for (int s = 0; s < 2; ++s) {
            const int row = wid * 8 + sl8 + 32 * s;       // e-local 0..63
#pragma unroll
            for (int j = 0; j < 4; ++j)
                vb[s][j] = Ub[(size_t)(kb + 4 * qg + j) * DD + e0 + row];
        }
    };

    loadU(0);
    for (int kb = 0; kb < IC; kb += 32) {
        __syncthreads();
#pragma unroll
        for (int s = 0; s < 4; ++s) {
            const int row = wid * 8 + sl8 + 32 * s;
            us4 h, l;
#pragma unroll
            for (int j = 0; j < 4; ++j) {
                h[j] = (unsigned short)(va[s][j] >> 16);
                l[j] = (unsigned short)(va[s][j] & 0xFFFFu);
            }
            *(us4*)&Ah[row][4 * qg] = h;
            *(us4*)&Al[row][4 * qg] = l;
        }
#pragma unroll
        for (int s = 0; s < 2; ++s) {
            const int row = wid * 8 + sl8 + 32 * s;
            us4 h, l;
#pragma unroll
            for (int j = 0; j < 4; ++j) {
                h[j] = (unsigned short)(vb[s][j] >> 16);
                l[j] = (unsigned short)(vb[s][j] & 0xFFFFu);
            }
            *(us4*)&Bh[row][4 * qg] = h;
            *(us4*)&Bl[row][4 * qg] = l;
        }
        __syncthreads();
        if (kb + 32 < IC) loadU(kb + 32);     // T14: next loads fly under MFMA
        s16x8 ah[4], al[4], bh[2], bl[2];
#pragma unroll
        for (int m = 0; m < 4; ++m) {
            const int r = wm * 64 + m * 16 + fr;
            ah[m] = *(const s16x8*)&Ah[r][kg * 8];
            al[m] = *(const s16x8*)&Al[r][kg * 8];
        }
#pragma unroll
        for (int n = 0; n < 2; ++n) {
            const int r = wn * 32 + n * 16 + fr;
            bh[n] = *(const s16x8*)&Bh[r][kg * 8];
            bl[n] = *(const s16x8*)&Bl[r][kg * 8];
        }
#pragma unroll
        for (int m = 0; m < 4; ++m)
#pragma unroll
            for (int n = 0; n < 2; ++n) {
                acc[m][n] = __builtin_amdgcn_mfma_f32_16x16x32_bf16(ah[m], bh[n], acc[m][n], 0, 0, 0);
                acc[m][n] = __builtin_amdgcn_mfma_f32_16x16x32_bf16(ah[m], bl[n], acc[m][n], 0, 0, 0);
                acc[m][n] = __builtin_amdgcn_mfma_f32_16x16x32_bf16(al[m], bh[n], acc[m][n], 0, 0, 0);
            }
    }

    // epilogue: bf16 hi/lo store (UNSCALED C) + fp32 trace
    float ts = 0.f;
    const int row_l = wm * 64 + (lane >> 4) * 4;
    const int col_l = wn * 32 + fr;
#pragma unroll
    for (int m = 0; m < 4; ++m)
#pragma unroll
        for (int n = 0; n < 2; ++n)
#pragma unroll
            for (int r = 0; r < 4; ++r) {
                const int gr = d0 + row_l + m * 16 + r;
                const int gc = e0 + col_l + n * 16;
                const float e = acc[m][n][r];
                const unsigned short h = f2b(e);
                const unsigned short l = f2b(e - b2f(h));
                const size_t o = mb + (size_t)gr * DD + gc;
                Ch[o] = h; Cl[o] = l;
                if (gr == gc) ts += e;
            }
    if ((tc >> 1) == tr) {
        red[t] = ts;
        __syncthreads();
        for (int s2 = 128; s2 > 0; s2 >>= 1) {
            if (t < s2) red[t] += red[t + s2];
            __syncthreads();
        }
        if (t == 0) atomicAdd(&Sc[bb], red[0]);
    }
}

// ---- E = (D/s)^2 via bf16-split MFMA, 64x64 tile, 1024 blocks --------------
// EXACT round-7-proven LDS body. LDS staging deduplicates row reads across
// waves (direct per-lane loads were 2x traffic + VGPR-bound: round-9 lesson).
// D symmetric => B-panel rows e0..e0+63 give B[k][j] directly in [j][k].
__global__ __launch_bounds__(256, 4)
void sqm_kernel(const unsigned short* __restrict__ Dh, const unsigned short* __restrict__ Dl,
                unsigned short* __restrict__ Eh, unsigned short* __restrict__ El,
                const float* __restrict__ s_in, float* __restrict__ s_out) {
    const int id   = blockIdx.x;          // 1024 = 64 batches x 16 tiles
    const int bb   = id & 63;             // id%8 == bb%8 -> batch XCD-local
    const int tile = id >> 6;             // 0..15 (4x4 of 64x64)
    const int tr = tile >> 2, tc = tile & 3;
    const int d0 = tr * 64, e0 = tc * 64;
    const int t    = threadIdx.x;
    const int lane = t & 63, wid = t >> 6;
    const int wm = wid >> 1, wn = wid & 1;            // 2x2 wave grid, 32x32/wave
    const int fr = lane & 15, kg = lane >> 4;
    const size_t mb = (size_t)bb * DDSQ;

    __shared__ unsigned short Ah[64][40];   // pitch 40 shorts (80 B), proven
    __shared__ unsigned short Al[64][40];
    __shared__ unsigned short Bh[64][40];
    __shared__ unsigned short Bl[64][40];
    __shared__ float red[256];

    const f32x4 z4 = {0.f, 0.f, 0.f, 0.f};
    f32x4 acc[2][2];
#pragma unroll
    for (int m = 0; m < 2; ++m)
#pragma unroll
        for (int n = 0; n < 2; ++n) acc[m][n] = z4;

    const float s   = s_in[bb];
    const float inv = 1.f / (s * s);
    const int row = t >> 2, q = t & 3;    // staging map: 64 rows x 4 k-quads

    for (int kb = 0; kb < DD; kb += 32) {
        const size_t ga = mb + (size_t)(d0 + row) * DD + kb + q * 8;
        const size_t gb = mb + (size_t)(e0 + row) * DD + kb + q * 8;
        const int4 rah = *(const int4*)&Dh[ga];
        const int4 ral = *(const int4*)&Dl[ga];
        const int4 rbh = *(const int4*)&Dh[gb];
        const int4 rbl = *(const int4*)&Dl[gb];
        __syncthreads();
        *(int4*)&Ah[row][q * 8] = rah;
        *(int4*)&Al[row][q * 8] = ral;
        *(int4*)&Bh[row][q * 8] = rbh;
        *(int4*)&Bl[row][q * 8] = rbl;
        __syncthreads();

        s16x8 ah[2], al[2], bh[2], bl[2];
#pragma unroll
        for (int m = 0; m < 2; ++m) {
            const int r = wm * 32 + m * 16 + fr;
            ah[m] = *(const s16x8*)&Ah[r][kg * 8];
            al[m] = *(const s16x8*)&Al[r][kg * 8];
        }
#pragma unroll
        for (int n = 0; n < 2; ++n) {
            const int r = wn * 32 + n * 16 + fr;
            bh[n] = *(const s16x8*)&Bh[r][kg * 8];
            bl[n] = *(const s16x8*)&Bl[r][kg * 8];
        }
#pragma unroll
        for (int m = 0; m < 2; ++m)
#pragma unroll
            for (int n = 0; n < 2; ++n) {
                acc[m][n] = __builtin_amdgcn_mfma_f32_16x16x32_bf16(ah[m], bh[n], acc[m][n], 0, 0, 0);
                acc[m][n] = __builtin_amdgcn_mfma_f32_16x16x32_bf16(ah[m], bl[n], acc[m][n], 0, 0, 0);
                acc[m][n] = __builtin_amdgcn_mfma_f32_16x16x32_bf16(al[m], bh[n], acc[m][n], 0, 0, 0);
            }
    }

    // epilogue: scale, trace, split to hi/lo bf16
    float ts = 0.f;
    const int row_l = wm * 32 + (lane >> 4) * 4;
    const int col_l = wn * 32 + fr;
#pragma unroll
    for (int m = 0; m < 2; ++m)
#pragma unroll
        for (int n = 0; n < 2; ++n)
#pragma unroll
            for (int r = 0; r < 4; ++r) {
                const int gr = d0 + row_l + m * 16 + r;
                const int gc = e0 + col_l + n * 16;
                const float e = acc[m][n][r] * inv;
                const unsigned short h = f2b(e);
                const unsigned short l = f2b(e - b2f(h));
                const size_t o = mb + (size_t)gr * DD + gc;
                Eh[o] = h; El[o] = l;
                if (gr == gc) ts += e;
            }
    if (tr == tc) {                       // 64x64 diag tiles partition diagonal
        red[t] = ts;
        __syncthreads();
        for (int s2 = 128; s2 > 0; s2 >>= 1) {
            if (t < s2) red[t] += red[t + s2];
            __syncthreads();
        }
        if (t == 0) atomicAdd(&s_out[bb], red[0]);
    }
}

// ------- finish: column start + NPI matvecs (no renorm; lambda1 ~ 1) --------
__global__ __launch_bounds__(256, 2) void finish_kernel(const unsigned short* __restrict__ Dh,
                                                        const unsigned short* __restrict__ Dl,
                                                        float* __restrict__ out) {
    const int b = blockIdx.x, t = threadIdx.x;
    const size_t mb = (size_t)b * DDSQ;
    __shared__ float vs[DD];
    __shared__ float red[DD];
    __shared__ int   ridx[DD];
    red[t] = b2f(Dh[mb + (size_t)t * DD + t]) + b2f(Dl[mb + (size_t)t * DD + t]);
    ridx[t] = t;
    __syncthreads();
    for (int s = 128; s > 0; s >>= 1) {
        if (t < s && red[t + s] > red[t]) { red[t] = red[t + s]; ridx[t] = ridx[t + s]; }
        __syncthreads();
    }
    const int jmax0 = ridx[0];
    __syncthreads();
    float v = b2f(Dh[mb + (size_t)jmax0 * DD + t]) + b2f(Dl[mb + (size_t)jmax0 * DD + t]);
    for (int it = 0; it < NPI; ++it) {
        vs[t] = v;
        __syncthreads();
        float a = 0.f;
        const unsigned short* rh = Dh + mb + (size_t)t * DD;
        const unsigned short* rl = Dl + mb + (size_t)t * DD;
#pragma unroll 4
        for (int j = 0; j < DD; j += 8) {
            const us8 h8 = *(const us8*)&rh[j];
            const us8 l8 = *(const us8*)&rl[j];
            a = fmaf(b2f(h8[0]) + b2f(l8[0]), vs[j + 0], a);
            a = fmaf(b2f(h8[1]) + b2f(l8[1]), vs[j + 1], a);
            a = fmaf(b2f(h8[2]) + b2f(l8[2]), vs[j + 2], a);
            a = fmaf(b2f(h8[3]) + b2f(l8[3]), vs[j + 3], a);
            a = fmaf(b2f(h8[4]) + b2f(l8[4]), vs[j + 4], a);
            a = fmaf(b2f(h8[5]) + b2f(l8[5]), vs[j + 5], a);
            a = fmaf(b2f(h8[6]) + b2f(l8[6]), vs[j + 6], a);
            a = fmaf(b2f(h8[7]) + b2f(l8[7]), vs[j + 7], a);
        }
        __syncthreads();
        v = a;
    }
    vs[t] = v;
    red[t] = v * v;
    __syncthreads();
    for (int s = 128; s > 0; s >>= 1) {
        if (t < s) red[t] += red[t + s];
        __syncthreads();
    }
    const float nrm = sqrtf(red[0]);
    __syncthreads();
    red[t] = fabsf(v);
    ridx[t] = t;
    __syncthreads();
    for (int s = 128; s > 0; s >>= 1) {
        if (t < s && red[t + s] > red[t]) { red[t] = red[t + s]; ridx[t] = ridx[t + s]; }
        __syncthreads();
    }
    const float sgn = (vs[ridx[0]] < 0.f) ? -1.f : 1.f;
    out[(size_t)b * DD + t] = sgn * v / nrm;
}

extern "C" void kernel_launch(void* const* d_in, const int* in_sizes, int n_in,
                              void* d_out, int out_size, void* d_ws, size_t ws_size,
                              hipStream_t stream) {
    const float* caps = (const float*)d_in[0];   // (64, 2048, 16)
    const float* W    = (const float*)d_in[1];   // (2048, 16, 256)
    float* out = (float*)d_out;                  // (64, 256)
    float* ws  = (float*)d_ws;

    // layout: Up packed = 8*PB @0 | X @8PB | Y @9PB | Sc @10PB  (~168 MB)
    unsigned* Up = (unsigned*)ws;
    unsigned short* Xh = (unsigned short*)(ws + (size_t)8 * PB);
    unsigned short* Xl = Xh + (size_t)NB * DDSQ;
    unsigned short* Yh = (unsigned short*)(ws + (size_t)9 * PB);
    unsigned short* Yl = Yh + (size_t)NB * DDSQ;
    float* Sc = ws + (size_t)10 * PB;

    hipMemsetAsync(Sc, 0, 2048 * sizeof(float), stream);

    u_kernel<<<IC, 256, 0, stream>>>(caps, W, Up);
    cmb_kernel<<<512, 256, 0, stream>>>(Up, Xh, Xl, Sc);   // C (unscaled) -> X

    unsigned short* ph = Xh; unsigned short* pl = Xl;
    unsigned short* qh = Yh; unsigned short* ql = Yl;
    for (int it = 0; it < NSQ; ++it) {
        sqm_kernel<<<1024, 256, 0, stream>>>(ph, pl, qh, ql,
                                             Sc + it * 64, Sc + (it + 1) * 64);
        unsigned short* t1 = ph; ph = qh; qh = t1;
        unsigned short* t2 = pl; pl = ql; ql = t2;
    }

    finish_kernel<<<NB, 256, 0, stream>>>(ph, pl, out);
}

// Round 11
// 378.753 us; speedup vs baseline: 1.5853x; 1.0092x over previous
//
#include <hip/hip_runtime.h>

#define NB  64
#define IC  2048
#define ID  16
#define DD  256
#define DDSQ 65536
#define PB  (DDSQ * NB)       // 4,194,304 floats = one full-batch fp32-sized buffer
#define NSQ 11                // matrix squarings
#define NPI 7                 // finish matvecs: exponent 2^11 * 8 = 16384

typedef __attribute__((ext_vector_type(8))) short          s16x8;  // 8 bf16 (4 VGPRs) MFMA frag
typedef __attribute__((ext_vector_type(4))) float          f32x4;  // MFMA acc
typedef __attribute__((ext_vector_type(4))) unsigned short us4;
typedef __attribute__((ext_vector_type(8))) unsigned short us8;

// fp32 -> bf16 (RNE) and back, via raw bits
__device__ __forceinline__ unsigned short f2b(float f) {
    union { float f; unsigned u; } c; c.f = f;
    const unsigned u = c.u + 0x7FFFu + ((c.u >> 16) & 1u);
    return (unsigned short)(u >> 16);
}
__device__ __forceinline__ float b2f(unsigned short h) {
    union { unsigned u; float f; } c; c.u = ((unsigned)h) << 16;
    return c.f;
}
// fp32 -> packed (hi bf16 << 16) | (lo bf16): 2-term split in one u32
__device__ __forceinline__ unsigned f2pk(float f) {
    const unsigned short h = f2b(f);
    const unsigned short l = f2b(f - b2f(h));
    return ((unsigned)h << 16) | (unsigned)l;
}

// ---------------- stage 1: u[b,c,:] = x[b,c,:] @ W_c (ALL 64 batches/block) -
// One block per capsule c (2048 blocks): W row read ONCE (round-10 proven).
__global__ __launch_bounds__(256, 4) void u_kernel(const float* __restrict__ caps,
                                                   const float* __restrict__ W,
                                                   unsigned* __restrict__ U) {
    const int c = blockIdx.x;
    const int t = threadIdx.x;
    __shared__ float xsT[ID][64];        // [dim][batch] (4 KB)
    {
        const int b = t >> 2, q = (t & 3) * 4;
        const float4 x4 = *(const float4*)&caps[((size_t)b * IC + c) * ID + q];
        xsT[q + 0][b] = x4.x; xsT[q + 1][b] = x4.y;
        xsT[q + 2][b] = x4.z; xsT[q + 3][b] = x4.w;
    }
    __syncthreads();
    float a[64];
#pragma unroll
    for (int b = 0; b < 64; ++b) a[b] = 0.f;
#pragma unroll
    for (int i = 0; i < ID; ++i) {
        const float wi = W[((size_t)c * ID + i) * DD + t];    // coalesced over t
#pragma unroll
        for (int g = 0; g < 16; ++g) {
            const float4 x = *(const float4*)&xsT[i][g * 4];
            a[g * 4 + 0] = fmaf(x.x, wi, a[g * 4 + 0]);
            a[g * 4 + 1] = fmaf(x.y, wi, a[g * 4 + 1]);
            a[g * 4 + 2] = fmaf(x.z, wi, a[g * 4 + 2]);
            a[g * 4 + 3] = fmaf(x.w, wi, a[g * 4 + 3]);
        }
    }
#pragma unroll
    for (int b = 0; b < 64; ++b)
        U[((size_t)b * IC + c) * DD + t] = f2pk(a[b]);
}

// ---- stage 2: C = U^T U (full K), BK=64, bf16 hi/lo out + trace ------------
// Round-10 proven body with k-chunk widened 32->64: halves the vmcnt-drain /
// barrier count (64 -> 32 pairs). Staging map applied twice per chunk; MFMA
// half-0 then half-1 == old chunk-pair order => bit-identical output.
__global__ __launch_bounds__(256, 2)
void cmb_kernel(const unsigned* __restrict__ Up,
                unsigned short* __restrict__ Ch, unsigned short* __restrict__ Cl,
                float* __restrict__ Sc) {
    const int id   = blockIdx.x;
    const int bb   = id & 63;
    const int tile = id >> 6;            // 0..7 (2x4 of 128x64)
    const int tr = tile >> 2, tc = tile & 3;
    const int d0 = tr * 128, e0 = tc * 64;
    const int t    = threadIdx.x;
    const int lane = t & 63, wid = t >> 6;
    const int wm = wid >> 1, wn = wid & 1;            // 2x2 wave grid
    const int fr = lane & 15, kg = lane >> 4;         // frag row, k-group
    const int sl8 = lane & 7, qg = lane >> 3;         // staging: row-in-octet, k-quad
    const size_t mb = (size_t)bb * DDSQ;

    __shared__ unsigned short Ah[128][72];   // [d][k], pitch 72 shorts (144 B)
    __shared__ unsigned short Al[128][72];
    __shared__ unsigned short Bh[64][72];    // [e][k]
    __shared__ unsigned short Bl[64][72];
    __shared__ float red[256];

    const f32x4 z4 = {0.f, 0.f, 0.f, 0.f};
    f32x4 acc[4][2];
#pragma unroll
    for (int m = 0; m < 4; ++m)
#pragma unroll
        for (int n = 0; n < 2; ++n) acc[m][n] = z4;

    const unsigned* Ub = Up + (size_t)bb * IC * DD;
    unsigned va[2][4][4], vb[2][2][4];
    auto loadU = [&](int kb) {
#pragma unroll
        for (int h = 0; h < 2; ++h) {
#pragma unroll
            for (int s = 0; s < 4; ++s) {
                const int row = wid * 8 + sl8 + 32 * s;       // d-local 0..127
#pragma unroll
                for (int j = 0; j < 4; ++j)
                    va[h][s][j] = Ub[(size_t)(kb + 32 * h + 4 * qg + j) * DD + d0 + row];
            }
#pragma unroll
            for (int s = 0; s < 2; ++s) {
                const int row = wid * 8 + sl8 + 32 * s;       // e-local 0..63
#pragma unroll
                for (int j = 0; j < 4; ++j)
                    vb[h][s][j] = Ub[(size_t)(kb + 32 * h + 4 * qg + j) * DD + e0 + row];
            }
        }
    };

    loadU(0);
    for (int kb = 0; kb < IC; kb += 64) {
        __syncthreads();
#pragma unroll
        for (int h = 0; h < 2; ++h) {
#pragma unroll
            for (int s = 0; s < 4; ++s) {
                const int row = wid * 8 + sl8 + 32 * s;
                us4 h4, l4;
#pragma unroll
                for (int j = 0; j < 4; ++j) {
                    h4[j] = (unsigned short)(va[h][s][j] >> 16);
                    l4[j] = (unsigned short)(va[h][s][j] & 0xFFFFu);
                }
                *(us4*)&Ah[row][4 * qg + 32 * h] = h4;
                *(us4*)&Al[row][4 * qg + 32 * h] = l4;
            }
#pragma unroll
            for (int s = 0; s < 2; ++s) {
                const int row = wid * 8 + sl8 + 32 * s;
                us4 h4, l4;
#pragma unroll
                for (int j = 0; j < 4; ++j) {
                    h4[j] = (unsigned short)(vb[h][s][j] >> 16);
                    l4[j] = (unsigned short)(vb[h][s][j] & 0xFFFFu);
                }
                *(us4*)&Bh[row][4 * qg + 32 * h] = h4;
                *(us4*)&Bl[row][4 * qg + 32 * h] = l4;
            }
        }
        __syncthreads();
        if (kb + 64 < IC) loadU(kb + 64);     // T14: next loads fly under MFMA
#pragma unroll
        for (int h = 0; h < 2; ++h) {
            const int ko = kg * 8 + 32 * h;
            s16x8 ah[4], al[4], bh[2], bl[2];
#pragma unroll
            for (int m = 0; m < 4; ++m) {
                const int r = wm * 64 + m * 16 + fr;
                ah[m] = *(const s16x8*)&Ah[r][ko];
                al[m] = *(const s16x8*)&Al[r][ko];
            }
#pragma unroll
            for (int n = 0; n < 2; ++n) {
                const int r = wn * 32 + n * 16 + fr;
                bh[n] = *(const s16x8*)&Bh[r][ko];
                bl[n] = *(const s16x8*)&Bl[r][ko];
            }
#pragma unroll
            for (int m = 0; m < 4; ++m)
#pragma unroll
                for (int n = 0; n < 2; ++n) {
                    acc[m][n] = __builtin_amdgcn_mfma_f32_16x16x32_bf16(ah[m], bh[n], acc[m][n], 0, 0, 0);
                    acc[m][n] = __builtin_amdgcn_mfma_f32_16x16x32_bf16(ah[m], bl[n], acc[m][n], 0, 0, 0);
                    acc[m][n] = __builtin_amdgcn_mfma_f32_16x16x32_bf16(al[m], bh[n], acc[m][n], 0, 0, 0);
                }
        }
    }

    // epilogue: bf16 hi/lo store (UNSCALED C) + fp32 trace
    float ts = 0.f;
    const int row_l = wm * 64 + (lane >> 4) * 4;
    const int col_l = wn * 32 + fr;
#pragma unroll
    for (int m = 0; m < 4; ++m)
#pragma unroll
        for (int n = 0; n < 2; ++n)
#pragma unroll
            for (int r = 0; r < 4; ++r) {
                const int gr = d0 + row_l + m * 16 + r;
                const int gc = e0 + col_l + n * 16;
                const float e = acc[m][n][r];
                const unsigned short h = f2b(e);
                const unsigned short l = f2b(e - b2f(h));
                const size_t o = mb + (size_t)gr * DD + gc;
                Ch[o] = h; Cl[o] = l;
                if (gr == gc) ts += e;
            }
    if ((tc >> 1) == tr) {
        red[t] = ts;
        __syncthreads();
        for (int s2 = 128; s2 > 0; s2 >>= 1) {
            if (t < s2) red[t] += red[t + s2];
            __syncthreads();
        }
        if (t == 0) atomicAdd(&Sc[bb], red[0]);
    }
}

// ---- E = (D/s)^2 via bf16-split MFMA, 64x64 tile, BK=64, 1024 blocks -------
// Round-10 proven body with k-chunk 32->64: barrier pairs 8 -> 4. LDS 37.9 KB
// x 4 blocks = 151.5 KB (4/CU preserved). MFMA half-order == old chunk order
// => bit-identical. D symmetric => B rows e0.. give B[k][j] in [j][k].
__global__ __launch_bounds__(256, 4)
void sqm_kernel(const unsigned short* __restrict__ Dh, const unsigned short* __restrict__ Dl,
                unsigned short* __restrict__ Eh, unsigned short* __restrict__ El,
                const float* __restrict__ s_in, float* __restrict__ s_out) {
    const int id   = blockIdx.x;          // 1024 = 64 batches x 16 tiles
    const int bb   = id & 63;             // id%8 == bb%8 -> batch XCD-local
    const int tile = id >> 6;             // 0..15 (4x4 of 64x64)
    const int tr = tile >> 2, tc = tile & 3;
    const int d0 = tr * 64, e0 = tc * 64;
    const int t    = threadIdx.x;
    const int lane = t & 63, wid = t >> 6;
    const int wm = wid >> 1, wn = wid & 1;            // 2x2 wave grid, 32x32/wave
    const int fr = lane & 15, kg = lane >> 4;
    const size_t mb = (size_t)bb * DDSQ;

    __shared__ unsigned short Ah[64][72];   // pitch 72 shorts (144 B)
    __shared__ unsigned short Al[64][72];
    __shared__ unsigned short Bh[64][72];
    __shared__ unsigned short Bl[64][72];
    __shared__ float red[256];

    const f32x4 z4 = {0.f, 0.f, 0.f, 0.f};
    f32x4 acc[2][2];
#pragma unroll
    for (int m = 0; m < 2; ++m)
#pragma unroll
        for (int n = 0; n < 2; ++n) acc[m][n] = z4;

    const float s   = s_in[bb];
    const float inv = 1.f / (s * s);
    const int row = t >> 2, q = t & 3;    // staging map: 64 rows x 4 k-quads

    for (int kb = 0; kb < DD; kb += 64) {
        const size_t ga = mb + (size_t)(d0 + row) * DD + kb + q * 8;
        const size_t gb = mb + (size_t)(e0 + row) * DD + kb + q * 8;
        const int4 rah0 = *(const int4*)&Dh[ga];
        const int4 rah1 = *(const int4*)&Dh[ga + 32];
        const int4 ral0 = *(const int4*)&Dl[ga];
        const int4 ral1 = *(const int4*)&Dl[ga + 32];
        const int4 rbh0 = *(const int4*)&Dh[gb];
        const int4 rbh1 = *(const int4*)&Dh[gb + 32];
        const int4 rbl0 = *(const int4*)&Dl[gb];
        const int4 rbl1 = *(const int4*)&Dl[gb + 32];
        __syncthreads();
        *(int4*)&Ah[row][q * 8]      = rah0;
        *(int4*)&Ah[row][q * 8 + 32] = rah1;
        *(int4*)&Al[row][q * 8]      = ral0;
        *(int4*)&Al[row][q * 8 + 32] = ral1;
        *(int4*)&Bh[row][q * 8]      = rbh0;
        *(int4*)&Bh[row][q * 8 + 32] = rbh1;
        *(int4*)&Bl[row][q * 8]      = rbl0;
        *(int4*)&Bl[row][q * 8 + 32] = rbl1;
        __syncthreads();

#pragma unroll
        for (int h = 0; h < 2; ++h) {
            const int ko = kg * 8 + 32 * h;
            s16x8 ah[2], al[2], bh[2], bl[2];
#pragma unroll
            for (int m = 0; m < 2; ++m) {
                const int r = wm * 32 + m * 16 + fr;
                ah[m] = *(const s16x8*)&Ah[r][ko];
                al[m] = *(const s16x8*)&Al[r][ko];
            }
#pragma unroll
            for (int n = 0; n < 2; ++n) {
                const int r = wn * 32 + n * 16 + fr;
                bh[n] = *(const s16x8*)&Bh[r][ko];
                bl[n] = *(const s16x8*)&Bl[r][ko];
            }
#pragma unroll
            for (int m = 0; m < 2; ++m)
#pragma unroll
                for (int n = 0; n < 2; ++n) {
                    acc[m][n] = __builtin_amdgcn_mfma_f32_16x16x32_bf16(ah[m], bh[n], acc[m][n], 0, 0, 0);
                    acc[m][n] = __builtin_amdgcn_mfma_f32_16x16x32_bf16(ah[m], bl[n], acc[m][n], 0, 0, 0);
                    acc[m][n] = __builtin_amdgcn_mfma_f32_16x16x32_bf16(al[m], bh[n], acc[m][n], 0, 0, 0);
                }
        }
    }

    // epilogue: scale, trace, split to hi/lo bf16
    float ts = 0.f;
    const int row_l = wm * 32 + (lane >> 4) * 4;
    const int col_l = wn * 32 + fr;
#pragma unroll
    for (int m = 0; m < 2; ++m)
#pragma unroll
        for (int n = 0; n < 2; ++n)
#pragma unroll
            for (int r = 0; r < 4; ++r) {
                const int gr = d0 + row_l + m * 16 + r;
                const int gc = e0 + col_l + n * 16;
                const float e = acc[m][n][r] * inv;
                const unsigned short h = f2b(e);
                const unsigned short l = f2b(e - b2f(h));
                const size_t o = mb + (size_t)gr * DD + gc;
                Eh[o] = h; El[o] = l;
                if (gr == gc) ts += e;
            }
    if (tr == tc) {                       // 64x64 diag tiles partition diagonal
        red[t] = ts;
        __syncthreads();
        for (int s2 = 128; s2 > 0; s2 >>= 1) {
            if (t < s2) red[t] += red[t + s2];
            __syncthreads();
        }
        if (t == 0) atomicAdd(&s_out[bb], red[0]);
    }
}

// ------- finish: column start + NPI matvecs (no renorm; lambda1 ~ 1) --------
__global__ __launch_bounds__(256, 2) void finish_kernel(const unsigned short* __restrict__ Dh,
                                                        const unsigned short* __restrict__ Dl,
                                                        float* __restrict__ out) {
    const int b = blockIdx.x, t = threadIdx.x;
    const size_t mb = (size_t)b * DDSQ;
    __shared__ float vs[DD];
    __shared__ float red[DD];
    __shared__ int   ridx[DD];
    red[t] = b2f(Dh[mb + (size_t)t * DD + t]) + b2f(Dl[mb + (size_t)t * DD + t]);
    ridx[t] = t;
    __syncthreads();
    for (int s = 128; s > 0; s >>= 1) {
        if (t < s && red[t + s] > red[t]) { red[t] = red[t + s]; ridx[t] = ridx[t + s]; }
        __syncthreads();
    }
    const int jmax0 = ridx[0];
    __syncthreads();
    float v = b2f(Dh[mb + (size_t)jmax0 * DD + t]) + b2f(Dl[mb + (size_t)jmax0 * DD + t]);
    for (int it = 0; it < NPI; ++it) {
        vs[t] = v;
        __syncthreads();
        float a = 0.f;
        const unsigned short* rh = Dh + mb + (size_t)t * DD;
        const unsigned short* rl = Dl + mb + (size_t)t * DD;
#pragma unroll 4
        for (int j = 0; j < DD; j += 8) {
            const us8 h8 = *(const us8*)&rh[j];
            const us8 l8 = *(const us8*)&rl[j];
            a = fmaf(b2f(h8[0]) + b2f(l8[0]), vs[j + 0], a);
            a = fmaf(b2f(h8[1]) + b2f(l8[1]), vs[j + 1], a);
            a = fmaf(b2f(h8[2]) + b2f(l8[2]), vs[j + 2], a);
            a = fmaf(b2f(h8[3]) + b2f(l8[3]), vs[j + 3], a);
            a = fmaf(b2f(h8[4]) + b2f(l8[4]), vs[j + 4], a);
            a = fmaf(b2f(h8[5]) + b2f(l8[5]), vs[j + 5], a);
            a = fmaf(b2f(h8[6]) + b2f(l8[6]), vs[j + 6], a);
            a = fmaf(b2f(h8[7]) + b2f(l8[7]), vs[j + 7], a);
        }
        __syncthreads();
        v = a;
    }
    vs[t] = v;
    red[t] = v * v;
    __syncthreads();
    for (int s = 128; s > 0; s >>= 1) {
        if (t < s) red[t] += red[t + s];
        __syncthreads();
    }
    const float nrm = sqrtf(red[0]);
    __syncthreads();
    red[t] = fabsf(v);
    ridx[t] = t;
    __syncthreads();
    for (int s = 128; s > 0; s >>= 1) {
        if (t < s && red[t + s] > red[t]) { red[t] = red[t + s]; ridx[t] = ridx[t + s]; }
        __syncthreads();
    }
    const float sgn = (vs[ridx[0]] < 0.f) ? -1.f : 1.f;
    out[(size_t)b * DD + t] = sgn * v / nrm;
}

extern "C" void kernel_launch(void* const* d_in, const int* in_sizes, int n_in,
                              void* d_out, int out_size, void* d_ws, size_t ws_size,
                              hipStream_t stream) {
    const float* caps = (const float*)d_in[0];   // (64, 2048, 16)
    const float* W    = (const float*)d_in[1];   // (2048, 16, 256)
    float* out = (float*)d_out;                  // (64, 256)
    float* ws  = (float*)d_ws;

    // layout: Up packed = 8*PB @0 | X @8PB | Y @9PB | Sc @10PB  (~168 MB)
    unsigned* Up = (unsigned*)ws;
    unsigned short* Xh = (unsigned short*)(ws + (size_t)8 * PB);
    unsigned short* Xl = Xh + (size_t)NB * DDSQ;
    unsigned short* Yh = (unsigned short*)(ws + (size_t)9 * PB);
    unsigned short* Yl = Yh + (size_t)NB * DDSQ;
    float* Sc = ws + (size_t)10 * PB;

    hipMemsetAsync(Sc, 0, 2048 * sizeof(float), stream);

    u_kernel<<<IC, 256, 0, stream>>>(caps, W, Up);
    cmb_kernel<<<512, 256, 0, stream>>>(Up, Xh, Xl, Sc);   // C (unscaled) -> X

    unsigned short* ph = Xh; unsigned short* pl = Xl;
    unsigned short* qh = Yh; unsigned short* ql = Yl;
    for (int it = 0; it < NSQ; ++it) {
        sqm_kernel<<<1024, 256, 0, stream>>>(ph, pl, qh, ql,
                                             Sc + it * 64, Sc + (it + 1) * 64);
        unsigned short* t1 = ph; ph = qh; qh = t1;
        unsigned short* t2 = pl; pl = ql; ql = t2;
    }

    finish_kernel<<<NB, 256, 0, stream>>>(ph, pl, out);
}

// Round 12
// 371.435 us; speedup vs baseline: 1.6166x; 1.0197x over previous
//
#include <hip/hip_runtime.h>

#define NB  64
#define IC  2048
#define ID  16
#define DD  256
#define DDSQ 65536
#define PB  (DDSQ * NB)       // 4,194,304 floats = one full-batch fp32-sized buffer
#define NSQ 11                // matrix squarings
#define NPI 7                 // finish matvecs: exponent 2^11 * 8 = 16384

typedef __attribute__((ext_vector_type(8))) short          s16x8;  // 8 bf16 (4 VGPRs) MFMA frag
typedef __attribute__((ext_vector_type(4))) float          f32x4;  // MFMA acc
typedef __attribute__((ext_vector_type(4))) unsigned short us4;
typedef __attribute__((ext_vector_type(8))) unsigned short us8;

// fp32 -> bf16 (RNE) and back, via raw bits
__device__ __forceinline__ unsigned short f2b(float f) {
    union { float f; unsigned u; } c; c.f = f;
    const unsigned u = c.u + 0x7FFFu + ((c.u >> 16) & 1u);
    return (unsigned short)(u >> 16);
}
__device__ __forceinline__ float b2f(unsigned short h) {
    union { unsigned u; float f; } c; c.u = ((unsigned)h) << 16;
    return c.f;
}
// fp32 -> packed (hi bf16 << 16) | (lo bf16): 2-term split in one u32
__device__ __forceinline__ unsigned f2pk(float f) {
    const unsigned short h = f2b(f);
    const unsigned short l = f2b(f - b2f(h));
    return ((unsigned)h << 16) | (unsigned)l;
}

// ---------------- stage 1: u[b,c,:] = x[b,c,:] @ W_c (ALL 64 batches/block) -
// One block per capsule c (2048 blocks): W row read ONCE (round-10 proven).
__global__ __launch_bounds__(256, 4) void u_kernel(const float* __restrict__ caps,
                                                   const float* __restrict__ W,
                                                   unsigned* __restrict__ U) {
    const int c = blockIdx.x;
    const int t = threadIdx.x;
    __shared__ float xsT[ID][64];        // [dim][batch] (4 KB)
    {
        const int b = t >> 2, q = (t & 3) * 4;
        const float4 x4 = *(const float4*)&caps[((size_t)b * IC + c) * ID + q];
        xsT[q + 0][b] = x4.x; xsT[q + 1][b] = x4.y;
        xsT[q + 2][b] = x4.z; xsT[q + 3][b] = x4.w;
    }
    __syncthreads();
    float a[64];
#pragma unroll
    for (int b = 0; b < 64; ++b) a[b] = 0.f;
#pragma unroll
    for (int i = 0; i < ID; ++i) {
        const float wi = W[((size_t)c * ID + i) * DD + t];    // coalesced over t
#pragma unroll
        for (int g = 0; g < 16; ++g) {
            const float4 x = *(const float4*)&xsT[i][g * 4];
            a[g * 4 + 0] = fmaf(x.x, wi, a[g * 4 + 0]);
            a[g * 4 + 1] = fmaf(x.y, wi, a[g * 4 + 1]);
            a[g * 4 + 2] = fmaf(x.z, wi, a[g * 4 + 2]);
            a[g * 4 + 3] = fmaf(x.w, wi, a[g * 4 + 3]);
        }
    }
#pragma unroll
    for (int b = 0; b < 64; ++b)
        U[((size_t)b * IC + c) * DD + t] = f2pk(a[b]);
}

// ---- stage 2: C = U^T U (full K), BK=32, bf16 hi/lo out + trace ------------
// EXACT round-10-proven body (BK=64 regressed: VGPR 56->88, LDS 2x, +9 us).
__global__ __launch_bounds__(256, 2)
void cmb_kernel(const unsigned* __restrict__ Up,
                unsigned short* __restrict__ Ch, unsigned short* __restrict__ Cl,
                float* __restrict__ Sc) {
    const int id   = blockIdx.x;
    const int bb   = id & 63;
    const int tile = id >> 6;            // 0..7 (2x4 of 128x64)
    const int tr = tile >> 2, tc = tile & 3;
    const int d0 = tr * 128, e0 = tc * 64;
    const int t    = threadIdx.x;
    const int lane = t & 63, wid = t >> 6;
    const int wm = wid >> 1, wn = wid & 1;            // 2x2 wave grid
    const int fr = lane & 15, kg = lane >> 4;         // frag row, k-group
    const int sl8 = lane & 7, qg = lane >> 3;         // staging: row-in-octet, k-quad
    const size_t mb = (size_t)bb * DDSQ;

    __shared__ unsigned short Ah[128][40];   // [d][k], pitch 40 shorts (80 B)
    __shared__ unsigned short Al[128][40];
    __shared__ unsigned short Bh[64][40];    // [e][k]
    __shared__ unsigned short Bl[64][40];
    __shared__ float red[256];

    const f32x4 z4 = {0.f, 0.f, 0.f, 0.f};
    f32x4 acc[4][2];
#pragma unroll
    for (int m = 0; m < 4; ++m)
#pragma unroll
        for (int n = 0; n < 2; ++n) acc[m][n] = z4;

    const unsigned* Ub = Up + (size_t)bb * IC * DD;
    unsigned va[4][4], vb[2][4];
    auto loadU = [&](int kb) {
#pragma unroll
        for (int s = 0; s < 4; ++s) {
            const int row = wid * 8 + sl8 + 32 * s;       // d-local 0..127
#pragma unroll
            for (int j = 0; j < 4; ++j)
                va[s][j] = Ub[(size_t)(kb + 4 * qg + j) * DD + d0 + row];
        }
#pragma unroll
        for (int s = 0; s < 2; ++s) {
            const int row = wid * 8 + sl8 + 32 * s;       // e-local 0..63
#pragma unroll
            for (int j = 0; j < 4; ++j)
                vb[s][j] = Ub[(size_t)(kb + 4 * qg + j) * DD + e0 + row];
        }
    };

    loadU(0);
    for (int kb = 0; kb < IC; kb += 32) {
        __syncthreads();
#pragma unroll
        for (int s = 0; s < 4; ++s) {
            const int row = wid * 8 + sl8 + 32 * s;
            us4 h, l;
#pragma unroll
            for (int j = 0; j < 4; ++j) {
                h[j] = (unsigned short)(va[s][j] >> 16);
                l[j] = (unsigned short)(va[s][j] & 0xFFFFu);
            }
            *(us4*)&Ah[row][4 * qg] = h;
            *(us4*)&Al[row][4 * qg] = l;
        }
#pragma unroll
        for (int s = 0; s < 2; ++s) {
            const int row = wid * 8 + sl8 + 32 * s;
            us4 h, l;
#pragma unroll
            for (int j = 0; j < 4; ++j) {
                h[j] = (unsigned short)(vb[s][j] >> 16);
                l[j] = (unsigned short)(vb[s][j] & 0xFFFFu);
            }
            *(us4*)&Bh[row][4 * qg] = h;
            *(us4*)&Bl[row][4 * qg] = l;
        }
        __syncthreads();
        if (kb + 32 < IC) loadU(kb + 32);     // T14: next loads fly under MFMA
        s16x8 ah[4], al[4], bh[2], bl[2];
#pragma unroll
        for (int m = 0; m < 4; ++m) {
            const int r = wm * 64 + m * 16 + fr;
            ah[m] = *(const s16x8*)&Ah[r][kg * 8];
            al[m] = *(const s16x8*)&Al[r][kg * 8];
        }
#pragma unroll
        for (int n = 0; n < 2; ++n) {
            const int r = wn * 32 + n * 16 + fr;
            bh[n] = *(const s16x8*)&Bh[r][kg * 8];
            bl[n] = *(const s16x8*)&Bl[r][kg * 8];
        }
#pragma unroll
        for (int m = 0; m < 4; ++m)
#pragma unroll
            for (int n = 0; n < 2; ++n) {
                acc[m][n] = __builtin_amdgcn_mfma_f32_16x16x32_bf16(ah[m], bh[n], acc[m][n], 0, 0, 0);
                acc[m][n] = __builtin_amdgcn_mfma_f32_16x16x32_bf16(ah[m], bl[n], acc[m][n], 0, 0, 0);
                acc[m][n] = __builtin_amdgcn_mfma_f32_16x16x32_bf16(al[m], bh[n], acc[m][n], 0, 0, 0);
            }
    }

    // epilogue: bf16 hi/lo store (UNSCALED C) + fp32 trace
    float ts = 0.f;
    const int row_l = wm * 64 + (lane >> 4) * 4;
    const int col_l = wn * 32 + fr;
#pragma unroll
    for (int m = 0; m < 4; ++m)
#pragma unroll
        for (int n = 0; n < 2; ++n)
#pragma unroll
            for (int r = 0; r < 4; ++r) {
                const int gr = d0 + row_l + m * 16 + r;
                const int gc = e0 + col_l + n * 16;
                const float e = acc[m][n][r];
                const unsigned short h = f2b(e);
                const unsigned short l = f2b(e - b2f(h));
                const size_t o = mb + (size_t)gr * DD + gc;
                Ch[o] = h; Cl[o] = l;
                if (gr == gc) ts += e;
            }
    if ((tc >> 1) == tr) {
        red[t] = ts;
        __syncthreads();
        for (int s2 = 128; s2 > 0; s2 >>= 1) {
            if (t < s2) red[t] += red[t + s2];
            __syncthreads();
        }
        if (t == 0) atomicAdd(&Sc[bb], red[0]);
    }
}

// ---- E = (D/s)^2, 64x64 tile, BK=64, UPPER-TRIANGLE ONLY (640 blocks) ------
// D is bit-exactly symmetric (C = U^T U; IEEE mul commutes; preserved by every
// squaring) => E[j][i] is bit-identical to E[i][j]. Compute 10 tiles (tr<=tc),
// mirror the 6 off-diagonal ones: per (m,n) fragment the 4 r-values land at
// (gc, gr0..gr0+3) = one aligned 8B us4 store per array. Bit-identical output.
__global__ __launch_bounds__(256, 4)
void sqm_kernel(const unsigned short* __restrict__ Dh, const unsigned short* __restrict__ Dl,
                unsigned short* __restrict__ Eh, unsigned short* __restrict__ El,
                const float* __restrict__ s_in, float* __restrict__ s_out) {
    const int id   = blockIdx.x;          // 640 = 64 batches x 10 tri-tiles
    const int bb   = id & 63;             // id%8 == bb%8 -> batch XCD-local
    const int tile = id >> 6;             // 0..9 upper-triangle enumeration
    int tr, tc;
    if (tile < 4)      { tr = 0; tc = tile; }
    else if (tile < 7) { tr = 1; tc = tile - 3; }
    else if (tile < 9) { tr = 2; tc = tile - 5; }
    else               { tr = 3; tc = 3; }
    const int d0 = tr * 64, e0 = tc * 64;
    const int t    = threadIdx.x;
    const int lane = t & 63, wid = t >> 6;
    const int wm = wid >> 1, wn = wid & 1;            // 2x2 wave grid, 32x32/wave
    const int fr = lane & 15, kg = lane >> 4;
    const size_t mb = (size_t)bb * DDSQ;

    __shared__ unsigned short Ah[64][72];   // pitch 72 shorts (144 B)
    __shared__ unsigned short Al[64][72];
    __shared__ unsigned short Bh[64][72];
    __shared__ unsigned short Bl[64][72];
    __shared__ float red[256];

    const f32x4 z4 = {0.f, 0.f, 0.f, 0.f};
    f32x4 acc[2][2];
#pragma unroll
    for (int m = 0; m < 2; ++m)
#pragma unroll
        for (int n = 0; n < 2; ++n) acc[m][n] = z4;

    const float s   = s_in[bb];
    const float inv = 1.f / (s * s);
    const int row = t >> 2, q = t & 3;    // staging map: 64 rows x 4 k-quads

    for (int kb = 0; kb < DD; kb += 64) {
        const size_t ga = mb + (size_t)(d0 + row) * DD + kb + q * 8;
        const size_t gb = mb + (size_t)(e0 + row) * DD + kb + q * 8;
        const int4 rah0 = *(const int4*)&Dh[ga];
        const int4 rah1 = *(const int4*)&Dh[ga + 32];
        const int4 ral0 = *(const int4*)&Dl[ga];
        const int4 ral1 = *(const int4*)&Dl[ga + 32];
        const int4 rbh0 = *(const int4*)&Dh[gb];
        const int4 rbh1 = *(const int4*)&Dh[gb + 32];
        const int4 rbl0 = *(const int4*)&Dl[gb];
        const int4 rbl1 = *(const int4*)&Dl[gb + 32];
        __syncthreads();
        *(int4*)&Ah[row][q * 8]      = rah0;
        *(int4*)&Ah[row][q * 8 + 32] = rah1;
        *(int4*)&Al[row][q * 8]      = ral0;
        *(int4*)&Al[row][q * 8 + 32] = ral1;
        *(int4*)&Bh[row][q * 8]      = rbh0;
        *(int4*)&Bh[row][q * 8 + 32] = rbh1;
        *(int4*)&Bl[row][q * 8]      = rbl0;
        *(int4*)&Bl[row][q * 8 + 32] = rbl1;
        __syncthreads();

#pragma unroll
        for (int h = 0; h < 2; ++h) {
            const int ko = kg * 8 + 32 * h;
            s16x8 ah[2], al[2], bh[2], bl[2];
#pragma unroll
            for (int m = 0; m < 2; ++m) {
                const int r = wm * 32 + m * 16 + fr;
                ah[m] = *(const s16x8*)&Ah[r][ko];
                al[m] = *(const s16x8*)&Al[r][ko];
            }
#pragma unroll
            for (int n = 0; n < 2; ++n) {
                const int r = wn * 32 + n * 16 + fr;
                bh[n] = *(const s16x8*)&Bh[r][ko];
                bl[n] = *(const s16x8*)&Bl[r][ko];
            }
#pragma unroll
            for (int m = 0; m < 2; ++m)
#pragma unroll
                for (int n = 0; n < 2; ++n) {
                    acc[m][n] = __builtin_amdgcn_mfma_f32_16x16x32_bf16(ah[m], bh[n], acc[m][n], 0, 0, 0);
                    acc[m][n] = __builtin_amdgcn_mfma_f32_16x16x32_bf16(ah[m], bl[n], acc[m][n], 0, 0, 0);
                    acc[m][n] = __builtin_amdgcn_mfma_f32_16x16x32_bf16(al[m], bh[n], acc[m][n], 0, 0, 0);
                }
        }
    }

    // epilogue: scale, trace, split to hi/lo bf16; mirror off-diag tiles
    float ts = 0.f;
    const int row_l = wm * 32 + (lane >> 4) * 4;
    const int col_l = wn * 32 + fr;
    const bool mir = (tr != tc);
#pragma unroll
    for (int m = 0; m < 2; ++m)
#pragma unroll
        for (int n = 0; n < 2; ++n) {
            const int gr0 = d0 + row_l + m * 16;
            const int gc  = e0 + col_l + n * 16;
            us4 h4, l4;
#pragma unroll
            for (int r = 0; r < 4; ++r) {
                const float e = acc[m][n][r] * inv;
                const unsigned short h = f2b(e);
                const unsigned short l = f2b(e - b2f(h));
                const size_t o = mb + (size_t)(gr0 + r) * DD + gc;
                Eh[o] = h; El[o] = l;
                h4[r] = h; l4[r] = l;
                if (gr0 + r == gc) ts += e;
            }
            if (mir) {                    // transposed us4: row gc, cols gr0..+3
                const size_t o2 = mb + (size_t)gc * DD + gr0;
                *(us4*)&Eh[o2] = h4;
                *(us4*)&El[o2] = l4;
            }
        }
    if (tr == tc) {                       // 4 diag tiles partition the diagonal
        red[t] = ts;
        __syncthreads();
        for (int s2 = 128; s2 > 0; s2 >>= 1) {
            if (t < s2) red[t] += red[t + s2];
            __syncthreads();
        }
        if (t == 0) atomicAdd(&s_out[bb], red[0]);
    }
}

// ------- finish: column start + NPI matvecs (no renorm; lambda1 ~ 1) --------
__global__ __launch_bounds__(256, 2) void finish_kernel(const unsigned short* __restrict__ Dh,
                                                        const unsigned short* __restrict__ Dl,
                                                        float* __restrict__ out) {
    const int b = blockIdx.x, t = threadIdx.x;
    const size_t mb = (size_t)b * DDSQ;
    __shared__ float vs[DD];
    __shared__ float red[DD];
    __shared__ int   ridx[DD];
    red[t] = b2f(Dh[mb + (size_t)t * DD + t]) + b2f(Dl[mb + (size_t)t * DD + t]);
    ridx[t] = t;
    __syncthreads();
    for (int s = 128; s > 0; s >>= 1) {
        if (t < s && red[t + s] > red[t]) { red[t] = red[t + s]; ridx[t] = ridx[t + s]; }
        __syncthreads();
    }
    const int jmax0 = ridx[0];
    __syncthreads();
    float v = b2f(Dh[mb + (size_t)jmax0 * DD + t]) + b2f(Dl[mb + (size_t)jmax0 * DD + t]);
    for (int it = 0; it < NPI; ++it) {
        vs[t] = v;
        __syncthreads();
        float a = 0.f;
        const unsigned short* rh = Dh + mb + (size_t)t * DD;
        const unsigned short* rl = Dl + mb + (size_t)t * DD;
#pragma unroll 4
        for (int j = 0; j < DD; j += 8) {
            const us8 h8 = *(const us8*)&rh[j];
            const us8 l8 = *(const us8*)&rl[j];
            a = fmaf(b2f(h8[0]) + b2f(l8[0]), vs[j + 0], a);
            a = fmaf(b2f(h8[1]) + b2f(l8[1]), vs[j + 1], a);
            a = fmaf(b2f(h8[2]) + b2f(l8[2]), vs[j + 2], a);
            a = fmaf(b2f(h8[3]) + b2f(l8[3]), vs[j + 3], a);
            a = fmaf(b2f(h8[4]) + b2f(l8[4]), vs[j + 4], a);
            a = fmaf(b2f(h8[5]) + b2f(l8[5]), vs[j + 5], a);
            a = fmaf(b2f(h8[6]) + b2f(l8[6]), vs[j + 6], a);
            a = fmaf(b2f(h8[7]) + b2f(l8[7]), vs[j + 7], a);
        }
        __syncthreads();
        v = a;
    }
    vs[t] = v;
    red[t] = v * v;
    __syncthreads();
    for (int s = 128; s > 0; s >>= 1) {
        if (t < s) red[t] += red[t + s];
        __syncthreads();
    }
    const float nrm = sqrtf(red[0]);
    __syncthreads();
    red[t] = fabsf(v);
    ridx[t] = t;
    __syncthreads();
    for (int s = 128; s > 0; s >>= 1) {
        if (t < s && red[t + s] > red[t]) { red[t] = red[t + s]; ridx[t] = ridx[t + s]; }
        __syncthreads();
    }
    const float sgn = (vs[ridx[0]] < 0.f) ? -1.f : 1.f;
    out[(size_t)b * DD + t] = sgn * v / nrm;
}

extern "C" void kernel_launch(void* const* d_in, const int* in_sizes, int n_in,
                              void* d_out, int out_size, void* d_ws, size_t ws_size,
                              hipStream_t stream) {
    const float* caps = (const float*)d_in[0];   // (64, 2048, 16)
    const float* W    = (const float*)d_in[1];   // (2048, 16, 256)
    float* out = (float*)d_out;                  // (64, 256)
    float* ws  = (float*)d_ws;

    // layout: Up packed = 8*PB @0 | X @8PB | Y @9PB | Sc @10PB  (~168 MB)
    unsigned* Up = (unsigned*)ws;
    unsigned short* Xh = (unsigned short*)(ws + (size_t)8 * PB);
    unsigned short* Xl = Xh + (size_t)NB * DDSQ;
    unsigned short* Yh = (unsigned short*)(ws + (size_t)9 * PB);
    unsigned short* Yl = Yh + (size_t)NB * DDSQ;
    float* Sc = ws + (size_t)10 * PB;

    hipMemsetAsync(Sc, 0, 2048 * sizeof(float), stream);

    u_kernel<<<IC, 256, 0, stream>>>(caps, W, Up);
    cmb_kernel<<<512, 256, 0, stream>>>(Up, Xh, Xl, Sc);   // C (unscaled) -> X

    unsigned short* ph = Xh; unsigned short* pl = Xl;
    unsigned short* qh = Yh; unsigned short* ql = Yl;
    for (int it = 0; it < NSQ; ++it) {
        sqm_kernel<<<640, 256, 0, stream>>>(ph, pl, qh, ql,
                                            Sc + it * 64, Sc + (it + 1) * 64);
        unsigned short* t1 = ph; ph = qh; qh = t1;
        unsigned short* t2 = pl; pl = ql; ql = t2;
    }

    finish_kernel<<<NB, 256, 0, stream>>>(ph, pl, out);
}